// Round 1
// baseline (188.215 us; speedup 1.0000x reference)
//
#include <hip/hip_runtime.h>

// GCN 2-layer. R7 = R6 pipeline with the same-address atomic tail removed:
//  k_sort  : bucket sort by dst>>7 (atomic reservation, fixed-stride regions), TPB=512
//  k_deg_u : per-bucket deg hist -> dinv/u, TPB=512, 8 wave-private copies
//  k_agg1  : per-bucket layer-1 scalar aggregate + fused 64-wide MLP -> w
//  k_agg2  : same for float2 + fused log_softmax; per-block partial written to a
//            PRIVATE slot (plain store) instead of atomicAdd on accum[0..1].
//            R6 evidence: 1564 device-scope fp atomics to ONE cache line from all
//            8 XCDs serialized ~30ns each ~= the whole 49.7us of k_agg2.
//  k_reduce_final : 1-block sum of the 782x2 partials + 1/N scale.
// packed word: bits[16:0]=src, bits[23:17]=dst&127.
// R5 lesson: do NOT stage u/w chunks in LDS -- per-chunk edge density makes
// staging a 25x traffic loss + 50 barriers/bucket.

#define TPB 512
#define SORT_BLK 256
#define BSHIFT 7
#define BNODES 128
#define MAXBUCK 1024
#define BSTRIDE 6144      // words per bucket region; mean 4092, sigma ~64 -> 32 sigma

// ---------------- bucket sort (count+place fused, atomic reservation) --------

__global__ __launch_bounds__(TPB) void k_sort(const int* __restrict__ ei, int E, int epb,
                                              int nbuck, int* __restrict__ gcur,
                                              unsigned* __restrict__ packed) {
    __shared__ int h[MAXBUCK];
    for (int b = threadIdx.x; b < nbuck; b += TPB) h[b] = 0;
    __syncthreads();
    const int4* d4 = (const int4*)(ei + E);
    int nq = epb >> 2;
    int q0 = blockIdx.x * nq;
    for (int j = threadIdx.x; j < nq; j += TPB) {
        int q = q0 + j;
        int e = q << 2;
        if (e + 3 < E) {
            int4 v = d4[q];
            atomicAdd(&h[v.x >> BSHIFT], 1);
            atomicAdd(&h[v.y >> BSHIFT], 1);
            atomicAdd(&h[v.z >> BSHIFT], 1);
            atomicAdd(&h[v.w >> BSHIFT], 1);
        } else {
            for (int k = 0; k < 4; ++k)
                if (e + k < E) atomicAdd(&h[(ei + E)[e + k] >> BSHIFT], 1);
        }
    }
    __syncthreads();
    for (int b = threadIdx.x; b < nbuck; b += TPB) {
        int c = h[b];
        h[b] = c ? atomicAdd(&gcur[b], c) : 0;
    }
    __syncthreads();
    const int4* s4 = (const int4*)ei;
    for (int j = threadIdx.x; j < nq; j += TPB) {
        int q = q0 + j;
        int e = q << 2;
        if (e + 3 < E) {
            int4 vs = s4[q];
            int4 vd = d4[q];
            int b, p;
            b = vd.x >> BSHIFT; p = atomicAdd(&h[b], 1);
            packed[b * BSTRIDE + p] = ((unsigned)(vd.x & (BNODES - 1)) << 17) | (unsigned)vs.x;
            b = vd.y >> BSHIFT; p = atomicAdd(&h[b], 1);
            packed[b * BSTRIDE + p] = ((unsigned)(vd.y & (BNODES - 1)) << 17) | (unsigned)vs.y;
            b = vd.z >> BSHIFT; p = atomicAdd(&h[b], 1);
            packed[b * BSTRIDE + p] = ((unsigned)(vd.z & (BNODES - 1)) << 17) | (unsigned)vs.z;
            b = vd.w >> BSHIFT; p = atomicAdd(&h[b], 1);
            packed[b * BSTRIDE + p] = ((unsigned)(vd.w & (BNODES - 1)) << 17) | (unsigned)vs.w;
        } else {
            for (int k = 0; k < 4; ++k) {
                int ee = e + k;
                if (ee < E) {
                    int s = ei[ee], d = ei[E + ee];
                    int b = d >> BSHIFT;
                    int p = atomicAdd(&h[b], 1);
                    packed[b * BSTRIDE + p] = ((unsigned)(d & (BNODES - 1)) << 17) | (unsigned)s;
                }
            }
        }
    }
}

// ---------------- per-bucket deg -> dinv/u ----------------

__global__ __launch_bounds__(TPB) void k_deg_u(const unsigned* __restrict__ packed,
                                               const int* __restrict__ gcur,
                                               const float* __restrict__ x,
                                               float* __restrict__ dinv,
                                               float* __restrict__ u, int N) {
    __shared__ int cnt[8][BNODES];
    for (int k = threadIdx.x; k < 8 * BNODES; k += TPB) ((int*)cnt)[k] = 0;
    __syncthreads();
    int b = blockIdx.x;
    int sz = gcur[b];
    const unsigned* base = packed + (size_t)b * BSTRIDE;
    const uint4* base4 = (const uint4*)base;
    int wv = threadIdx.x >> 6;
    int nq4 = sz >> 2;
    int half = nq4 >> 1;
    for (int j = threadIdx.x; j < half; j += TPB) {
        uint4 p = base4[j];
        uint4 q = base4[j + half];
        atomicAdd(&cnt[wv][(p.x >> 17) & 127], 1);
        atomicAdd(&cnt[wv][(p.y >> 17) & 127], 1);
        atomicAdd(&cnt[wv][(p.z >> 17) & 127], 1);
        atomicAdd(&cnt[wv][(p.w >> 17) & 127], 1);
        atomicAdd(&cnt[wv][(q.x >> 17) & 127], 1);
        atomicAdd(&cnt[wv][(q.y >> 17) & 127], 1);
        atomicAdd(&cnt[wv][(q.z >> 17) & 127], 1);
        atomicAdd(&cnt[wv][(q.w >> 17) & 127], 1);
    }
    for (int j = half * 8 + threadIdx.x; j < sz; j += TPB) {   // tail < 12 words
        unsigned p = base[j];
        atomicAdd(&cnt[wv][(p >> 17) & 127], 1);
    }
    __syncthreads();
    if (threadIdx.x < BNODES) {
        int t = threadIdx.x;
        int node = (b << BSHIFT) + t;
        if (node < N) {
            int deg = 0;
            #pragma unroll
            for (int c = 0; c < 8; ++c) deg += cnt[c][t];
            float di = rsqrtf((float)(deg + 1));   // +1 self-loop
            dinv[node] = di;
            u[node] = di * x[node];
        }
    }
}

// ---------------- layer-1 aggregation + MLP ----------------

__global__ __launch_bounds__(TPB) void k_agg1(const unsigned* __restrict__ packed,
                                              const int* __restrict__ gcur,
                                              const float* __restrict__ dinv,
                                              const float* __restrict__ u,
                                              const float* __restrict__ W1,
                                              const float* __restrict__ b1,
                                              const float* __restrict__ W2,
                                              float2* __restrict__ w, int N) {
    __shared__ float acc[8][BNODES];
    __shared__ float sW1[64], sb1[64], sW2[128];
    if (threadIdx.x < 64) { sW1[threadIdx.x] = W1[threadIdx.x]; sb1[threadIdx.x] = b1[threadIdx.x]; }
    else if (threadIdx.x >= 64 && threadIdx.x < 192) sW2[threadIdx.x - 64] = W2[threadIdx.x - 64];
    for (int k = threadIdx.x; k < 8 * BNODES; k += TPB) ((float*)acc)[k] = 0.f;
    __syncthreads();
    int b = blockIdx.x;
    int sz = gcur[b];
    const unsigned* base = packed + (size_t)b * BSTRIDE;
    const uint4* base4 = (const uint4*)base;
    int wv = threadIdx.x >> 6;
    int nq4 = sz >> 2;
    int half = nq4 >> 1;
    for (int j = threadIdx.x; j < half; j += TPB) {
        uint4 p = base4[j];
        uint4 q = base4[j + half];
        float v0 = u[p.x & 0x1FFFF];
        float v1 = u[p.y & 0x1FFFF];
        float v2 = u[p.z & 0x1FFFF];
        float v3 = u[p.w & 0x1FFFF];
        float v4 = u[q.x & 0x1FFFF];
        float v5 = u[q.y & 0x1FFFF];
        float v6 = u[q.z & 0x1FFFF];
        float v7 = u[q.w & 0x1FFFF];
        atomicAdd(&acc[wv][(p.x >> 17) & 127], v0);
        atomicAdd(&acc[wv][(p.y >> 17) & 127], v1);
        atomicAdd(&acc[wv][(p.z >> 17) & 127], v2);
        atomicAdd(&acc[wv][(p.w >> 17) & 127], v3);
        atomicAdd(&acc[wv][(q.x >> 17) & 127], v4);
        atomicAdd(&acc[wv][(q.y >> 17) & 127], v5);
        atomicAdd(&acc[wv][(q.z >> 17) & 127], v6);
        atomicAdd(&acc[wv][(q.w >> 17) & 127], v7);
    }
    for (int j = half * 8 + threadIdx.x; j < sz; j += TPB) {
        unsigned p = base[j];
        atomicAdd(&acc[wv][(p >> 17) & 127], u[p & 0x1FFFF]);
    }
    __syncthreads();
    if (threadIdx.x < BNODES) {
        int t = threadIdx.x;
        int node = (b << BSHIFT) + t;
        if (node < N) {
            float s = 0.f;
            #pragma unroll
            for (int c = 0; c < 8; ++c) s += acc[c][t];
            float di = dinv[node];
            float sv = di * (s + u[node]);       // self-loop term dinv*u
            float z0 = 0.f, z1 = 0.f;
            #pragma unroll
            for (int j = 0; j < 64; ++j) {
                float h = fmaxf(fmaf(sv, sW1[j], sb1[j]), 0.f);
                z0 = fmaf(h, sW2[2 * j], z0);
                z1 = fmaf(h, sW2[2 * j + 1], z1);
            }
            w[node] = make_float2(di * z0, di * z1);  // pre-scaled by dinv[src]
        }
    }
}

// ---------------- layer-2 aggregation + log_softmax + per-block partial ------

__global__ __launch_bounds__(TPB) void k_agg2(const unsigned* __restrict__ packed,
                                              const int* __restrict__ gcur,
                                              const float* __restrict__ dinv,
                                              const float2* __restrict__ w,
                                              const float* __restrict__ b2,
                                              float* __restrict__ accum, int N) {
    __shared__ float accx[8][BNODES], accy[8][BNODES];
    for (int k = threadIdx.x; k < 8 * BNODES; k += TPB) {
        ((float*)accx)[k] = 0.f;
        ((float*)accy)[k] = 0.f;
    }
    __syncthreads();
    int b = blockIdx.x;
    int sz = gcur[b];
    const unsigned* base = packed + (size_t)b * BSTRIDE;
    const uint4* base4 = (const uint4*)base;
    int wv = threadIdx.x >> 6;
    int nq4 = sz >> 2;
    int half = nq4 >> 1;
    for (int j = threadIdx.x; j < half; j += TPB) {
        uint4 p = base4[j];
        uint4 q = base4[j + half];
        float2 v0 = w[p.x & 0x1FFFF];
        float2 v1 = w[p.y & 0x1FFFF];
        float2 v2 = w[p.z & 0x1FFFF];
        float2 v3 = w[p.w & 0x1FFFF];
        float2 v4 = w[q.x & 0x1FFFF];
        float2 v5 = w[q.y & 0x1FFFF];
        float2 v6 = w[q.z & 0x1FFFF];
        float2 v7 = w[q.w & 0x1FFFF];
        int l0 = (p.x >> 17) & 127, l1 = (p.y >> 17) & 127;
        int l2 = (p.z >> 17) & 127, l3 = (p.w >> 17) & 127;
        int l4 = (q.x >> 17) & 127, l5 = (q.y >> 17) & 127;
        int l6 = (q.z >> 17) & 127, l7 = (q.w >> 17) & 127;
        atomicAdd(&accx[wv][l0], v0.x); atomicAdd(&accy[wv][l0], v0.y);
        atomicAdd(&accx[wv][l1], v1.x); atomicAdd(&accy[wv][l1], v1.y);
        atomicAdd(&accx[wv][l2], v2.x); atomicAdd(&accy[wv][l2], v2.y);
        atomicAdd(&accx[wv][l3], v3.x); atomicAdd(&accy[wv][l3], v3.y);
        atomicAdd(&accx[wv][l4], v4.x); atomicAdd(&accy[wv][l4], v4.y);
        atomicAdd(&accx[wv][l5], v5.x); atomicAdd(&accy[wv][l5], v5.y);
        atomicAdd(&accx[wv][l6], v6.x); atomicAdd(&accy[wv][l6], v6.y);
        atomicAdd(&accx[wv][l7], v7.x); atomicAdd(&accy[wv][l7], v7.y);
    }
    for (int j = half * 8 + threadIdx.x; j < sz; j += TPB) {
        unsigned p = base[j];
        float2 v = w[p & 0x1FFFF];
        int l = (p >> 17) & 127;
        atomicAdd(&accx[wv][l], v.x);
        atomicAdd(&accy[wv][l], v.y);
    }
    __syncthreads();
    float l0 = 0.f, l1 = 0.f;
    if (threadIdx.x < BNODES) {
        int t = threadIdx.x;
        int node = (b << BSHIFT) + t;
        if (node < N) {
            float sx = 0.f, sy = 0.f;
            #pragma unroll
            for (int c = 0; c < 8; ++c) { sx += accx[c][t]; sy += accy[c][t]; }
            float di = dinv[node];
            float2 wi = w[node];
            float a0 = di * (sx + wi.x) + b2[0];
            float a1 = di * (sy + wi.y) + b2[1];
            float m = fmaxf(a0, a1);
            float lse = m + logf(expf(a0 - m) + expf(a1 - m));
            l0 = a0 - lse;
            l1 = a1 - lse;
        }
    }
    #pragma unroll
    for (int off = 32; off > 0; off >>= 1) {
        l0 += __shfl_down(l0, off, 64);
        l1 += __shfl_down(l1, off, 64);
    }
    __shared__ float s0[TPB / 64], s1[TPB / 64];
    int wid = threadIdx.x >> 6, lane = threadIdx.x & 63;
    if (lane == 0) { s0[wid] = l0; s1[wid] = l1; }
    __syncthreads();
    if (threadIdx.x == 0) {
        float t0 = 0.f, t1 = 0.f;
        #pragma unroll
        for (int k = 0; k < TPB / 64; ++k) { t0 += s0[k]; t1 += s1[k]; }
        // per-block private slot: plain store, NO same-address device atomic.
        accum[2 * b]     = t0;
        accum[2 * b + 1] = t1;
    }
}

// ---------------- final reduction over per-block partials ----------------

#define RTPB 1024
__global__ __launch_bounds__(RTPB) void k_reduce_final(const float* __restrict__ accum,
                                                       int nb, float* __restrict__ out,
                                                       float invN) {
    float t0 = 0.f, t1 = 0.f;
    for (int i = threadIdx.x; i < nb; i += RTPB) {
        t0 += accum[2 * i];
        t1 += accum[2 * i + 1];
    }
    #pragma unroll
    for (int off = 32; off > 0; off >>= 1) {
        t0 += __shfl_down(t0, off, 64);
        t1 += __shfl_down(t1, off, 64);
    }
    __shared__ float s0[RTPB / 64], s1[RTPB / 64];
    int wid = threadIdx.x >> 6, lane = threadIdx.x & 63;
    if (lane == 0) { s0[wid] = t0; s1[wid] = t1; }
    __syncthreads();
    if (threadIdx.x == 0) {
        float a = 0.f, b = 0.f;
        #pragma unroll
        for (int k = 0; k < RTPB / 64; ++k) { a += s0[k]; b += s1[k]; }
        out[0] = a * invN;
        out[1] = b * invN;
    }
}

__global__ void k_finalize(const float* __restrict__ accum, float* __restrict__ out, float invN) {
    out[0] = accum[0] * invN;
    out[1] = accum[1] * invN;
}

// ---------------- fallback (global-atomic path) ----------------

#define FTPB 256
__global__ void k_hist(const int* __restrict__ dst, int E, int* __restrict__ deg) {
    int e = blockIdx.x * FTPB + threadIdx.x;
    if (e < E) atomicAdd(&deg[dst[e]], 1);
}
__global__ void k_dinv_u(const int* __restrict__ deg, const float* __restrict__ x,
                         float* __restrict__ dinv, float* __restrict__ u, int N) {
    int i = blockIdx.x * FTPB + threadIdx.x;
    if (i < N) {
        float di = rsqrtf((float)(deg[i] + 1));
        dinv[i] = di;
        u[i] = di * x[i];
    }
}
__global__ void k_scatter1(const int* __restrict__ ei, int E,
                           const float* __restrict__ u, float* __restrict__ t) {
    int e = blockIdx.x * FTPB + threadIdx.x;
    if (e < E) atomicAdd(&t[ei[E + e]], u[ei[e]]);
}
__global__ void k_node_mid_fb(const float* __restrict__ dinv, const float* __restrict__ u,
                              const float* __restrict__ t,
                              const float* __restrict__ W1, const float* __restrict__ b1,
                              const float* __restrict__ W2, float2* __restrict__ w, int N) {
    __shared__ float sW1[64], sb1[64], sW2[128];
    if (threadIdx.x < 64) { sW1[threadIdx.x] = W1[threadIdx.x]; sb1[threadIdx.x] = b1[threadIdx.x]; }
    if (threadIdx.x < 128) sW2[threadIdx.x] = W2[threadIdx.x];
    __syncthreads();
    int i = blockIdx.x * FTPB + threadIdx.x;
    if (i < N) {
        float di = dinv[i];
        float s = di * (t[i] + u[i]);
        float z0 = 0.f, z1 = 0.f;
        #pragma unroll
        for (int j = 0; j < 64; ++j) {
            float h = fmaxf(fmaf(s, sW1[j], sb1[j]), 0.f);
            z0 = fmaf(h, sW2[2 * j], z0);
            z1 = fmaf(h, sW2[2 * j + 1], z1);
        }
        w[i] = make_float2(di * z0, di * z1);
    }
}
__global__ void k_scatter2(const int* __restrict__ ei, int E,
                           const float2* __restrict__ w, float* __restrict__ acc) {
    int e = blockIdx.x * FTPB + threadIdx.x;
    if (e < E) {
        float2 ws = w[ei[e]];
        int d = ei[E + e];
        atomicAdd(&acc[2 * d], ws.x);
        atomicAdd(&acc[2 * d + 1], ws.y);
    }
}
__global__ void k_node_out_fb(const float* __restrict__ dinv, const float2* __restrict__ w,
                              const float2* __restrict__ acc, const float* __restrict__ b2,
                              float* __restrict__ accum, int N) {
    int i = blockIdx.x * FTPB + threadIdx.x;
    float l0 = 0.f, l1 = 0.f;
    if (i < N) {
        float di = dinv[i];
        float2 a = acc[i];
        float2 ww = w[i];
        float a0 = di * (a.x + ww.x) + b2[0];
        float a1 = di * (a.y + ww.y) + b2[1];
        float m = fmaxf(a0, a1);
        float lse = m + logf(expf(a0 - m) + expf(a1 - m));
        l0 = a0 - lse;
        l1 = a1 - lse;
    }
    #pragma unroll
    for (int off = 32; off > 0; off >>= 1) {
        l0 += __shfl_down(l0, off, 64);
        l1 += __shfl_down(l1, off, 64);
    }
    __shared__ float s0[FTPB / 64], s1[FTPB / 64];
    int wid = threadIdx.x >> 6, lane = threadIdx.x & 63;
    if (lane == 0) { s0[wid] = l0; s1[wid] = l1; }
    __syncthreads();
    if (threadIdx.x == 0) {
        float t0 = 0.f, t1 = 0.f;
        #pragma unroll
        for (int k = 0; k < FTPB / 64; ++k) { t0 += s0[k]; t1 += s1[k]; }
        atomicAdd(&accum[0], t0);
        atomicAdd(&accum[1], t1);
    }
}

extern "C" void kernel_launch(void* const* d_in, const int* in_sizes, int n_in,
                              void* d_out, int out_size, void* d_ws, size_t ws_size,
                              hipStream_t stream) {
    const float* x  = (const float*)d_in[0];
    const int*   ei = (const int*)d_in[1];
    const float* W1 = (const float*)d_in[2];
    const float* b1 = (const float*)d_in[3];
    const float* W2 = (const float*)d_in[4];
    const float* b2 = (const float*)d_in[5];
    float* out = (float*)d_out;

    const int N = in_sizes[0];
    const int E = in_sizes[1] / 2;
    const int nbuck = (N + BNODES - 1) >> BSHIFT;
    const int gridN = (N + FTPB - 1) / FTPB;
    const int gridE = (E + FTPB - 1) / FTPB;

    size_t offPacked = 0;
    size_t offW      = offPacked + (size_t)nbuck * BSTRIDE * 4;
    size_t offDinv   = offW + (size_t)N * 8;
    size_t offU      = offDinv + (size_t)N * 4;
    size_t offGcur   = offU + (size_t)N * 4;
    size_t offAccum  = offGcur + (size_t)nbuck * 4;
    size_t need      = offAccum + (size_t)2 * nbuck * 4;

    if (ws_size >= need && nbuck <= MAXBUCK && N <= (1 << 17)) {
        unsigned* packed = (unsigned*)((char*)d_ws + offPacked);
        float2*   w      = (float2*)((char*)d_ws + offW);
        float*    dinv   = (float*)((char*)d_ws + offDinv);
        float*    u      = (float*)((char*)d_ws + offU);
        int*      gcur   = (int*)((char*)d_ws + offGcur);
        float*    accum  = (float*)((char*)d_ws + offAccum);

        hipMemsetAsync(gcur, 0, (size_t)nbuck * 4, stream);

        int epb = (((E + SORT_BLK - 1) / SORT_BLK) + 3) & ~3;

        k_sort<<<SORT_BLK, TPB, 0, stream>>>(ei, E, epb, nbuck, gcur, packed);
        k_deg_u<<<nbuck, TPB, 0, stream>>>(packed, gcur, x, dinv, u, N);
        k_agg1<<<nbuck, TPB, 0, stream>>>(packed, gcur, dinv, u, W1, b1, W2, w, N);
        k_agg2<<<nbuck, TPB, 0, stream>>>(packed, gcur, dinv, (const float2*)w, b2, accum, N);
        k_reduce_final<<<1, RTPB, 0, stream>>>(accum, nbuck, out, 1.0f / (float)N);
    } else {
        int*   deg   = (int*)d_ws;
        float* t     = (float*)(deg + N);
        float* acc   = t + N;
        float* accum = acc + 2 * N;
        float* dinv  = accum + 2;
        float* u     = dinv + N;
        float2* w    = (float2*)(u + N);
        hipMemsetAsync(d_ws, 0, (size_t)(4 * N + 2) * sizeof(float), stream);
        k_hist<<<gridE, FTPB, 0, stream>>>(ei + E, E, deg);
        k_dinv_u<<<gridN, FTPB, 0, stream>>>(deg, x, dinv, u, N);
        k_scatter1<<<gridE, FTPB, 0, stream>>>(ei, E, u, t);
        k_node_mid_fb<<<gridN, FTPB, 0, stream>>>(dinv, u, t, W1, b1, W2, w, N);
        k_scatter2<<<gridE, FTPB, 0, stream>>>(ei, E, w, acc);
        k_node_out_fb<<<gridN, FTPB, 0, stream>>>(dinv, w, (const float2*)acc, b2, accum, N);
        k_finalize<<<1, 64, 0, stream>>>(accum, out, 1.0f / (float)N);
    }
}

// Round 2
// 187.461 us; speedup vs baseline: 1.0040x; 1.0040x over previous
//
#include <hip/hip_runtime.h>

// GCN 2-layer. R8 = R7 with L1-bypass (device-scope) loads on the random gathers.
// R7 post-mortem: removing the same-address atomic tail was neutral (49.7->49.2us)
// -> k_agg2 is NOT atomic-bound. New theory: random gathers (3.2M x 8B from w[],
// ~12K distinct 64B lines per CU, zero per-CU reuse) are L1-miss-tracker bound:
// ~32 outstanding misses x ~250cyc L2 latency ~= 39us, matching the observed 49us
// with all pipes idle. Fix: __hip_atomic_load(RELAXED, SCOPE_AGENT) => global_load
// with sc0=1, bypassing L1 straight to L2 (w/u are fully L2-resident). Applied to
// the 8-wide random gathers in k_agg1/k_agg2 only; coalesced reads keep L1 path.
//  k_sort  : bucket sort by dst>>7 (atomic reservation, fixed-stride regions)
//  k_deg_u : per-bucket deg hist -> dinv/u
//  k_agg1  : per-bucket layer-1 scalar aggregate + fused 64-wide MLP -> w
//  k_agg2  : float2 aggregate + log_softmax; per-block partial to private slot
//  k_reduce_final : 1-block sum of partials + 1/N scale
// packed word: bits[16:0]=src, bits[23:17]=dst&127.

#define TPB 512
#define SORT_BLK 256
#define BSHIFT 7
#define BNODES 128
#define MAXBUCK 1024
#define BSTRIDE 6144      // words per bucket region; mean 4092, sigma ~64 -> 32 sigma

// ---- device-scope (L1-bypass) gather loads ----
__device__ __forceinline__ float ld_dev_f32(const float* p) {
    return __hip_atomic_load(p, __ATOMIC_RELAXED, __HIP_MEMORY_SCOPE_AGENT);
}
__device__ __forceinline__ float2 ld_dev_f32x2(const float2* p) {
    unsigned long long r =
        __hip_atomic_load((const unsigned long long*)p, __ATOMIC_RELAXED, __HIP_MEMORY_SCOPE_AGENT);
    float2 v;
    v.x = __uint_as_float((unsigned)(r & 0xFFFFFFFFull));
    v.y = __uint_as_float((unsigned)(r >> 32));
    return v;
}

// ---------------- bucket sort (count+place fused, atomic reservation) --------

__global__ __launch_bounds__(TPB) void k_sort(const int* __restrict__ ei, int E, int epb,
                                              int nbuck, int* __restrict__ gcur,
                                              unsigned* __restrict__ packed) {
    __shared__ int h[MAXBUCK];
    for (int b = threadIdx.x; b < nbuck; b += TPB) h[b] = 0;
    __syncthreads();
    const int4* d4 = (const int4*)(ei + E);
    int nq = epb >> 2;
    int q0 = blockIdx.x * nq;
    for (int j = threadIdx.x; j < nq; j += TPB) {
        int q = q0 + j;
        int e = q << 2;
        if (e + 3 < E) {
            int4 v = d4[q];
            atomicAdd(&h[v.x >> BSHIFT], 1);
            atomicAdd(&h[v.y >> BSHIFT], 1);
            atomicAdd(&h[v.z >> BSHIFT], 1);
            atomicAdd(&h[v.w >> BSHIFT], 1);
        } else {
            for (int k = 0; k < 4; ++k)
                if (e + k < E) atomicAdd(&h[(ei + E)[e + k] >> BSHIFT], 1);
        }
    }
    __syncthreads();
    for (int b = threadIdx.x; b < nbuck; b += TPB) {
        int c = h[b];
        h[b] = c ? atomicAdd(&gcur[b], c) : 0;
    }
    __syncthreads();
    const int4* s4 = (const int4*)ei;
    for (int j = threadIdx.x; j < nq; j += TPB) {
        int q = q0 + j;
        int e = q << 2;
        if (e + 3 < E) {
            int4 vs = s4[q];
            int4 vd = d4[q];
            int b, p;
            b = vd.x >> BSHIFT; p = atomicAdd(&h[b], 1);
            packed[b * BSTRIDE + p] = ((unsigned)(vd.x & (BNODES - 1)) << 17) | (unsigned)vs.x;
            b = vd.y >> BSHIFT; p = atomicAdd(&h[b], 1);
            packed[b * BSTRIDE + p] = ((unsigned)(vd.y & (BNODES - 1)) << 17) | (unsigned)vs.y;
            b = vd.z >> BSHIFT; p = atomicAdd(&h[b], 1);
            packed[b * BSTRIDE + p] = ((unsigned)(vd.z & (BNODES - 1)) << 17) | (unsigned)vs.z;
            b = vd.w >> BSHIFT; p = atomicAdd(&h[b], 1);
            packed[b * BSTRIDE + p] = ((unsigned)(vd.w & (BNODES - 1)) << 17) | (unsigned)vs.w;
        } else {
            for (int k = 0; k < 4; ++k) {
                int ee = e + k;
                if (ee < E) {
                    int s = ei[ee], d = ei[E + ee];
                    int b = d >> BSHIFT;
                    int p = atomicAdd(&h[b], 1);
                    packed[b * BSTRIDE + p] = ((unsigned)(d & (BNODES - 1)) << 17) | (unsigned)s;
                }
            }
        }
    }
}

// ---------------- per-bucket deg -> dinv/u ----------------

__global__ __launch_bounds__(TPB) void k_deg_u(const unsigned* __restrict__ packed,
                                               const int* __restrict__ gcur,
                                               const float* __restrict__ x,
                                               float* __restrict__ dinv,
                                               float* __restrict__ u, int N) {
    __shared__ int cnt[8][BNODES];
    for (int k = threadIdx.x; k < 8 * BNODES; k += TPB) ((int*)cnt)[k] = 0;
    __syncthreads();
    int b = blockIdx.x;
    int sz = gcur[b];
    const unsigned* base = packed + (size_t)b * BSTRIDE;
    const uint4* base4 = (const uint4*)base;
    int wv = threadIdx.x >> 6;
    int nq4 = sz >> 2;
    int half = nq4 >> 1;
    for (int j = threadIdx.x; j < half; j += TPB) {
        uint4 p = base4[j];
        uint4 q = base4[j + half];
        atomicAdd(&cnt[wv][(p.x >> 17) & 127], 1);
        atomicAdd(&cnt[wv][(p.y >> 17) & 127], 1);
        atomicAdd(&cnt[wv][(p.z >> 17) & 127], 1);
        atomicAdd(&cnt[wv][(p.w >> 17) & 127], 1);
        atomicAdd(&cnt[wv][(q.x >> 17) & 127], 1);
        atomicAdd(&cnt[wv][(q.y >> 17) & 127], 1);
        atomicAdd(&cnt[wv][(q.z >> 17) & 127], 1);
        atomicAdd(&cnt[wv][(q.w >> 17) & 127], 1);
    }
    for (int j = half * 8 + threadIdx.x; j < sz; j += TPB) {   // tail < 12 words
        unsigned p = base[j];
        atomicAdd(&cnt[wv][(p >> 17) & 127], 1);
    }
    __syncthreads();
    if (threadIdx.x < BNODES) {
        int t = threadIdx.x;
        int node = (b << BSHIFT) + t;
        if (node < N) {
            int deg = 0;
            #pragma unroll
            for (int c = 0; c < 8; ++c) deg += cnt[c][t];
            float di = rsqrtf((float)(deg + 1));   // +1 self-loop
            dinv[node] = di;
            u[node] = di * x[node];
        }
    }
}

// ---------------- layer-1 aggregation + MLP ----------------

__global__ __launch_bounds__(TPB) void k_agg1(const unsigned* __restrict__ packed,
                                              const int* __restrict__ gcur,
                                              const float* __restrict__ dinv,
                                              const float* __restrict__ u,
                                              const float* __restrict__ W1,
                                              const float* __restrict__ b1,
                                              const float* __restrict__ W2,
                                              float2* __restrict__ w, int N) {
    __shared__ float acc[8][BNODES];
    __shared__ float sW1[64], sb1[64], sW2[128];
    if (threadIdx.x < 64) { sW1[threadIdx.x] = W1[threadIdx.x]; sb1[threadIdx.x] = b1[threadIdx.x]; }
    else if (threadIdx.x >= 64 && threadIdx.x < 192) sW2[threadIdx.x - 64] = W2[threadIdx.x - 64];
    for (int k = threadIdx.x; k < 8 * BNODES; k += TPB) ((float*)acc)[k] = 0.f;
    __syncthreads();
    int b = blockIdx.x;
    int sz = gcur[b];
    const unsigned* base = packed + (size_t)b * BSTRIDE;
    const uint4* base4 = (const uint4*)base;
    int wv = threadIdx.x >> 6;
    int nq4 = sz >> 2;
    int half = nq4 >> 1;
    for (int j = threadIdx.x; j < half; j += TPB) {
        uint4 p = base4[j];
        uint4 q = base4[j + half];
        float v0 = ld_dev_f32(u + (p.x & 0x1FFFF));
        float v1 = ld_dev_f32(u + (p.y & 0x1FFFF));
        float v2 = ld_dev_f32(u + (p.z & 0x1FFFF));
        float v3 = ld_dev_f32(u + (p.w & 0x1FFFF));
        float v4 = ld_dev_f32(u + (q.x & 0x1FFFF));
        float v5 = ld_dev_f32(u + (q.y & 0x1FFFF));
        float v6 = ld_dev_f32(u + (q.z & 0x1FFFF));
        float v7 = ld_dev_f32(u + (q.w & 0x1FFFF));
        atomicAdd(&acc[wv][(p.x >> 17) & 127], v0);
        atomicAdd(&acc[wv][(p.y >> 17) & 127], v1);
        atomicAdd(&acc[wv][(p.z >> 17) & 127], v2);
        atomicAdd(&acc[wv][(p.w >> 17) & 127], v3);
        atomicAdd(&acc[wv][(q.x >> 17) & 127], v4);
        atomicAdd(&acc[wv][(q.y >> 17) & 127], v5);
        atomicAdd(&acc[wv][(q.z >> 17) & 127], v6);
        atomicAdd(&acc[wv][(q.w >> 17) & 127], v7);
    }
    for (int j = half * 8 + threadIdx.x; j < sz; j += TPB) {
        unsigned p = base[j];
        atomicAdd(&acc[wv][(p >> 17) & 127], ld_dev_f32(u + (p & 0x1FFFF)));
    }
    __syncthreads();
    if (threadIdx.x < BNODES) {
        int t = threadIdx.x;
        int node = (b << BSHIFT) + t;
        if (node < N) {
            float s = 0.f;
            #pragma unroll
            for (int c = 0; c < 8; ++c) s += acc[c][t];
            float di = dinv[node];
            float sv = di * (s + u[node]);       // self-loop term dinv*u
            float z0 = 0.f, z1 = 0.f;
            #pragma unroll
            for (int j = 0; j < 64; ++j) {
                float h = fmaxf(fmaf(sv, sW1[j], sb1[j]), 0.f);
                z0 = fmaf(h, sW2[2 * j], z0);
                z1 = fmaf(h, sW2[2 * j + 1], z1);
            }
            w[node] = make_float2(di * z0, di * z1);  // pre-scaled by dinv[src]
        }
    }
}

// ---------------- layer-2 aggregation + log_softmax + per-block partial ------

__global__ __launch_bounds__(TPB) void k_agg2(const unsigned* __restrict__ packed,
                                              const int* __restrict__ gcur,
                                              const float* __restrict__ dinv,
                                              const float2* __restrict__ w,
                                              const float* __restrict__ b2,
                                              float* __restrict__ accum, int N) {
    __shared__ float accx[8][BNODES], accy[8][BNODES];
    for (int k = threadIdx.x; k < 8 * BNODES; k += TPB) {
        ((float*)accx)[k] = 0.f;
        ((float*)accy)[k] = 0.f;
    }
    __syncthreads();
    int b = blockIdx.x;
    int sz = gcur[b];
    const unsigned* base = packed + (size_t)b * BSTRIDE;
    const uint4* base4 = (const uint4*)base;
    int wv = threadIdx.x >> 6;
    int nq4 = sz >> 2;
    int half = nq4 >> 1;
    for (int j = threadIdx.x; j < half; j += TPB) {
        uint4 p = base4[j];
        uint4 q = base4[j + half];
        float2 v0 = ld_dev_f32x2(w + (p.x & 0x1FFFF));
        float2 v1 = ld_dev_f32x2(w + (p.y & 0x1FFFF));
        float2 v2 = ld_dev_f32x2(w + (p.z & 0x1FFFF));
        float2 v3 = ld_dev_f32x2(w + (p.w & 0x1FFFF));
        float2 v4 = ld_dev_f32x2(w + (q.x & 0x1FFFF));
        float2 v5 = ld_dev_f32x2(w + (q.y & 0x1FFFF));
        float2 v6 = ld_dev_f32x2(w + (q.z & 0x1FFFF));
        float2 v7 = ld_dev_f32x2(w + (q.w & 0x1FFFF));
        int l0 = (p.x >> 17) & 127, l1 = (p.y >> 17) & 127;
        int l2 = (p.z >> 17) & 127, l3 = (p.w >> 17) & 127;
        int l4 = (q.x >> 17) & 127, l5 = (q.y >> 17) & 127;
        int l6 = (q.z >> 17) & 127, l7 = (q.w >> 17) & 127;
        atomicAdd(&accx[wv][l0], v0.x); atomicAdd(&accy[wv][l0], v0.y);
        atomicAdd(&accx[wv][l1], v1.x); atomicAdd(&accy[wv][l1], v1.y);
        atomicAdd(&accx[wv][l2], v2.x); atomicAdd(&accy[wv][l2], v2.y);
        atomicAdd(&accx[wv][l3], v3.x); atomicAdd(&accy[wv][l3], v3.y);
        atomicAdd(&accx[wv][l4], v4.x); atomicAdd(&accy[wv][l4], v4.y);
        atomicAdd(&accx[wv][l5], v5.x); atomicAdd(&accy[wv][l5], v5.y);
        atomicAdd(&accx[wv][l6], v6.x); atomicAdd(&accy[wv][l6], v6.y);
        atomicAdd(&accx[wv][l7], v7.x); atomicAdd(&accy[wv][l7], v7.y);
    }
    for (int j = half * 8 + threadIdx.x; j < sz; j += TPB) {
        unsigned p = base[j];
        float2 v = ld_dev_f32x2(w + (p & 0x1FFFF));
        int l = (p >> 17) & 127;
        atomicAdd(&accx[wv][l], v.x);
        atomicAdd(&accy[wv][l], v.y);
    }
    __syncthreads();
    float l0 = 0.f, l1 = 0.f;
    if (threadIdx.x < BNODES) {
        int t = threadIdx.x;
        int node = (b << BSHIFT) + t;
        if (node < N) {
            float sx = 0.f, sy = 0.f;
            #pragma unroll
            for (int c = 0; c < 8; ++c) { sx += accx[c][t]; sy += accy[c][t]; }
            float di = dinv[node];
            float2 wi = w[node];
            float a0 = di * (sx + wi.x) + b2[0];
            float a1 = di * (sy + wi.y) + b2[1];
            float m = fmaxf(a0, a1);
            float lse = m + logf(expf(a0 - m) + expf(a1 - m));
            l0 = a0 - lse;
            l1 = a1 - lse;
        }
    }
    #pragma unroll
    for (int off = 32; off > 0; off >>= 1) {
        l0 += __shfl_down(l0, off, 64);
        l1 += __shfl_down(l1, off, 64);
    }
    __shared__ float s0[TPB / 64], s1[TPB / 64];
    int wid = threadIdx.x >> 6, lane = threadIdx.x & 63;
    if (lane == 0) { s0[wid] = l0; s1[wid] = l1; }
    __syncthreads();
    if (threadIdx.x == 0) {
        float t0 = 0.f, t1 = 0.f;
        #pragma unroll
        for (int k = 0; k < TPB / 64; ++k) { t0 += s0[k]; t1 += s1[k]; }
        // per-block private slot: plain store, NO same-address device atomic.
        accum[2 * b]     = t0;
        accum[2 * b + 1] = t1;
    }
}

// ---------------- final reduction over per-block partials ----------------

#define RTPB 1024
__global__ __launch_bounds__(RTPB) void k_reduce_final(const float* __restrict__ accum,
                                                       int nb, float* __restrict__ out,
                                                       float invN) {
    float t0 = 0.f, t1 = 0.f;
    for (int i = threadIdx.x; i < nb; i += RTPB) {
        t0 += accum[2 * i];
        t1 += accum[2 * i + 1];
    }
    #pragma unroll
    for (int off = 32; off > 0; off >>= 1) {
        t0 += __shfl_down(t0, off, 64);
        t1 += __shfl_down(t1, off, 64);
    }
    __shared__ float s0[RTPB / 64], s1[RTPB / 64];
    int wid = threadIdx.x >> 6, lane = threadIdx.x & 63;
    if (lane == 0) { s0[wid] = t0; s1[wid] = t1; }
    __syncthreads();
    if (threadIdx.x == 0) {
        float a = 0.f, b = 0.f;
        #pragma unroll
        for (int k = 0; k < RTPB / 64; ++k) { a += s0[k]; b += s1[k]; }
        out[0] = a * invN;
        out[1] = b * invN;
    }
}

__global__ void k_finalize(const float* __restrict__ accum, float* __restrict__ out, float invN) {
    out[0] = accum[0] * invN;
    out[1] = accum[1] * invN;
}

// ---------------- fallback (global-atomic path) ----------------

#define FTPB 256
__global__ void k_hist(const int* __restrict__ dst, int E, int* __restrict__ deg) {
    int e = blockIdx.x * FTPB + threadIdx.x;
    if (e < E) atomicAdd(&deg[dst[e]], 1);
}
__global__ void k_dinv_u(const int* __restrict__ deg, const float* __restrict__ x,
                         float* __restrict__ dinv, float* __restrict__ u, int N) {
    int i = blockIdx.x * FTPB + threadIdx.x;
    if (i < N) {
        float di = rsqrtf((float)(deg[i] + 1));
        dinv[i] = di;
        u[i] = di * x[i];
    }
}
__global__ void k_scatter1(const int* __restrict__ ei, int E,
                           const float* __restrict__ u, float* __restrict__ t) {
    int e = blockIdx.x * FTPB + threadIdx.x;
    if (e < E) atomicAdd(&t[ei[E + e]], u[ei[e]]);
}
__global__ void k_node_mid_fb(const float* __restrict__ dinv, const float* __restrict__ u,
                              const float* __restrict__ t,
                              const float* __restrict__ W1, const float* __restrict__ b1,
                              const float* __restrict__ W2, float2* __restrict__ w, int N) {
    __shared__ float sW1[64], sb1[64], sW2[128];
    if (threadIdx.x < 64) { sW1[threadIdx.x] = W1[threadIdx.x]; sb1[threadIdx.x] = b1[threadIdx.x]; }
    if (threadIdx.x < 128) sW2[threadIdx.x] = W2[threadIdx.x];
    __syncthreads();
    int i = blockIdx.x * FTPB + threadIdx.x;
    if (i < N) {
        float di = dinv[i];
        float s = di * (t[i] + u[i]);
        float z0 = 0.f, z1 = 0.f;
        #pragma unroll
        for (int j = 0; j < 64; ++j) {
            float h = fmaxf(fmaf(s, sW1[j], sb1[j]), 0.f);
            z0 = fmaf(h, sW2[2 * j], z0);
            z1 = fmaf(h, sW2[2 * j + 1], z1);
        }
        w[i] = make_float2(di * z0, di * z1);
    }
}
__global__ void k_scatter2(const int* __restrict__ ei, int E,
                           const float2* __restrict__ w, float* __restrict__ acc) {
    int e = blockIdx.x * FTPB + threadIdx.x;
    if (e < E) {
        float2 ws = w[ei[e]];
        int d = ei[E + e];
        atomicAdd(&acc[2 * d], ws.x);
        atomicAdd(&acc[2 * d + 1], ws.y);
    }
}
__global__ void k_node_out_fb(const float* __restrict__ dinv, const float2* __restrict__ w,
                              const float2* __restrict__ acc, const float* __restrict__ b2,
                              float* __restrict__ accum, int N) {
    int i = blockIdx.x * FTPB + threadIdx.x;
    float l0 = 0.f, l1 = 0.f;
    if (i < N) {
        float di = dinv[i];
        float2 a = acc[i];
        float2 ww = w[i];
        float a0 = di * (a.x + ww.x) + b2[0];
        float a1 = di * (a.y + ww.y) + b2[1];
        float m = fmaxf(a0, a1);
        float lse = m + logf(expf(a0 - m) + expf(a1 - m));
        l0 = a0 - lse;
        l1 = a1 - lse;
    }
    #pragma unroll
    for (int off = 32; off > 0; off >>= 1) {
        l0 += __shfl_down(l0, off, 64);
        l1 += __shfl_down(l1, off, 64);
    }
    __shared__ float s0[FTPB / 64], s1[FTPB / 64];
    int wid = threadIdx.x >> 6, lane = threadIdx.x & 63;
    if (lane == 0) { s0[wid] = l0; s1[wid] = l1; }
    __syncthreads();
    if (threadIdx.x == 0) {
        float t0 = 0.f, t1 = 0.f;
        #pragma unroll
        for (int k = 0; k < FTPB / 64; ++k) { t0 += s0[k]; t1 += s1[k]; }
        atomicAdd(&accum[0], t0);
        atomicAdd(&accum[1], t1);
    }
}

extern "C" void kernel_launch(void* const* d_in, const int* in_sizes, int n_in,
                              void* d_out, int out_size, void* d_ws, size_t ws_size,
                              hipStream_t stream) {
    const float* x  = (const float*)d_in[0];
    const int*   ei = (const int*)d_in[1];
    const float* W1 = (const float*)d_in[2];
    const float* b1 = (const float*)d_in[3];
    const float* W2 = (const float*)d_in[4];
    const float* b2 = (const float*)d_in[5];
    float* out = (float*)d_out;

    const int N = in_sizes[0];
    const int E = in_sizes[1] / 2;
    const int nbuck = (N + BNODES - 1) >> BSHIFT;
    const int gridN = (N + FTPB - 1) / FTPB;
    const int gridE = (E + FTPB - 1) / FTPB;

    size_t offPacked = 0;
    size_t offW      = offPacked + (size_t)nbuck * BSTRIDE * 4;
    size_t offDinv   = offW + (size_t)N * 8;
    size_t offU      = offDinv + (size_t)N * 4;
    size_t offGcur   = offU + (size_t)N * 4;
    size_t offAccum  = offGcur + (size_t)nbuck * 4;
    size_t need      = offAccum + (size_t)2 * nbuck * 4;

    if (ws_size >= need && nbuck <= MAXBUCK && N <= (1 << 17)) {
        unsigned* packed = (unsigned*)((char*)d_ws + offPacked);
        float2*   w      = (float2*)((char*)d_ws + offW);
        float*    dinv   = (float*)((char*)d_ws + offDinv);
        float*    u      = (float*)((char*)d_ws + offU);
        int*      gcur   = (int*)((char*)d_ws + offGcur);
        float*    accum  = (float*)((char*)d_ws + offAccum);

        hipMemsetAsync(gcur, 0, (size_t)nbuck * 4, stream);

        int epb = (((E + SORT_BLK - 1) / SORT_BLK) + 3) & ~3;

        k_sort<<<SORT_BLK, TPB, 0, stream>>>(ei, E, epb, nbuck, gcur, packed);
        k_deg_u<<<nbuck, TPB, 0, stream>>>(packed, gcur, x, dinv, u, N);
        k_agg1<<<nbuck, TPB, 0, stream>>>(packed, gcur, dinv, u, W1, b1, W2, w, N);
        k_agg2<<<nbuck, TPB, 0, stream>>>(packed, gcur, dinv, (const float2*)w, b2, accum, N);
        k_reduce_final<<<1, RTPB, 0, stream>>>(accum, nbuck, out, 1.0f / (float)N);
    } else {
        int*   deg   = (int*)d_ws;
        float* t     = (float*)(deg + N);
        float* acc   = t + N;
        float* accum = acc + 2 * N;
        float* dinv  = accum + 2;
        float* u     = dinv + N;
        float2* w    = (float2*)(u + N);
        hipMemsetAsync(d_ws, 0, (size_t)(4 * N + 2) * sizeof(float), stream);
        k_hist<<<gridE, FTPB, 0, stream>>>(ei + E, E, deg);
        k_dinv_u<<<gridN, FTPB, 0, stream>>>(deg, x, dinv, u, N);
        k_scatter1<<<gridE, FTPB, 0, stream>>>(ei, E, u, t);
        k_node_mid_fb<<<gridN, FTPB, 0, stream>>>(dinv, u, t, W1, b1, W2, w, N);
        k_scatter2<<<gridE, FTPB, 0, stream>>>(ei, E, w, acc);
        k_node_out_fb<<<gridN, FTPB, 0, stream>>>(dinv, w, (const float2*)acc, b2, accum, N);
        k_finalize<<<1, 64, 0, stream>>>(accum, out, 1.0f / (float)N);
    }
}

// Round 3
// 164.781 us; speedup vs baseline: 1.1422x; 1.1376x over previous
//
#include <hip/hip_runtime.h>

// GCN 2-layer. R9 = CSR restructure: aggregation kernels are ATOMIC-FREE.
// R7/R8 post-mortem: neither global-atomic tail nor L1-bypass moved k_agg2
// (49.6us, VALUBusy 2.4%, all pipes idle). Cycle models price the visible
// per-CU work at <10us -> the cost is structural: 19.2M LDS lane-atomics
// pipeline-wide + one-shot loops (1 iter/thread = zero latency hiding).
// R9: k_csr extends deg_u to build a per-bucket CSR (per-wave hist it already
// has + 128-wide scan + wave-private cursors -> LDS staging -> coalesced
// IN-PLACE writeback of the packed region, now sorted by dst-local node).
// k_agg1/k_agg2 become segmented reductions: 4 threads/node, ~8-edge register
// loop, shfl combine. No LDS atomics, no per-edge barriers, looped gathers.
//  k_sort  : unchanged bucket sort by dst>>7
//  k_csr   : deg/dinv/u + within-bucket counting sort (wave-private cursors)
//  k_agg1  : atomic-free segmented sum of u[src] + fused 64-wide MLP -> w
//  k_agg2  : atomic-free segmented float2 sum + log_softmax + block partial
//  k_reduce_final : sum partials + 1/N
// packed word (post-sort): bits[16:0]=src. rptr[b*128+t] = exclusive offsets.

#define TPB 512
#define SORT_BLK 256
#define BSHIFT 7
#define BNODES 128
#define MAXBUCK 1024
#define BSTRIDE 6144      // words per bucket region; mean 4092, sigma ~64 -> 32 sigma

// ---------------- bucket sort (count+place fused, atomic reservation) --------

__global__ __launch_bounds__(TPB) void k_sort(const int* __restrict__ ei, int E, int epb,
                                              int nbuck, int* __restrict__ gcur,
                                              unsigned* __restrict__ packed) {
    __shared__ int h[MAXBUCK];
    for (int b = threadIdx.x; b < nbuck; b += TPB) h[b] = 0;
    __syncthreads();
    const int4* d4 = (const int4*)(ei + E);
    int nq = epb >> 2;
    int q0 = blockIdx.x * nq;
    for (int j = threadIdx.x; j < nq; j += TPB) {
        int q = q0 + j;
        int e = q << 2;
        if (e + 3 < E) {
            int4 v = d4[q];
            atomicAdd(&h[v.x >> BSHIFT], 1);
            atomicAdd(&h[v.y >> BSHIFT], 1);
            atomicAdd(&h[v.z >> BSHIFT], 1);
            atomicAdd(&h[v.w >> BSHIFT], 1);
        } else {
            for (int k = 0; k < 4; ++k)
                if (e + k < E) atomicAdd(&h[(ei + E)[e + k] >> BSHIFT], 1);
        }
    }
    __syncthreads();
    for (int b = threadIdx.x; b < nbuck; b += TPB) {
        int c = h[b];
        h[b] = c ? atomicAdd(&gcur[b], c) : 0;
    }
    __syncthreads();
    const int4* s4 = (const int4*)ei;
    for (int j = threadIdx.x; j < nq; j += TPB) {
        int q = q0 + j;
        int e = q << 2;
        if (e + 3 < E) {
            int4 vs = s4[q];
            int4 vd = d4[q];
            int b, p;
            b = vd.x >> BSHIFT; p = atomicAdd(&h[b], 1);
            packed[b * BSTRIDE + p] = ((unsigned)(vd.x & (BNODES - 1)) << 17) | (unsigned)vs.x;
            b = vd.y >> BSHIFT; p = atomicAdd(&h[b], 1);
            packed[b * BSTRIDE + p] = ((unsigned)(vd.y & (BNODES - 1)) << 17) | (unsigned)vs.y;
            b = vd.z >> BSHIFT; p = atomicAdd(&h[b], 1);
            packed[b * BSTRIDE + p] = ((unsigned)(vd.z & (BNODES - 1)) << 17) | (unsigned)vs.z;
            b = vd.w >> BSHIFT; p = atomicAdd(&h[b], 1);
            packed[b * BSTRIDE + p] = ((unsigned)(vd.w & (BNODES - 1)) << 17) | (unsigned)vs.w;
        } else {
            for (int k = 0; k < 4; ++k) {
                int ee = e + k;
                if (ee < E) {
                    int s = ei[ee], d = ei[E + ee];
                    int b = d >> BSHIFT;
                    int p = atomicAdd(&h[b], 1);
                    packed[b * BSTRIDE + p] = ((unsigned)(d & (BNODES - 1)) << 17) | (unsigned)s;
                }
            }
        }
    }
}

// ------- per-bucket deg -> dinv/u + in-place counting sort (CSR build) -------

__global__ __launch_bounds__(TPB) void k_csr(unsigned* __restrict__ packed,
                                             const int* __restrict__ gcur,
                                             const float* __restrict__ x,
                                             float* __restrict__ dinv,
                                             float* __restrict__ u,
                                             int* __restrict__ rptr, int N) {
    __shared__ int cnt[8][BNODES];
    __shared__ int eptr[BNODES];
    __shared__ unsigned stage[BSTRIDE];
    for (int k = threadIdx.x; k < 8 * BNODES; k += TPB) ((int*)cnt)[k] = 0;
    __syncthreads();
    int b = blockIdx.x;
    int sz = gcur[b];
    unsigned* base = packed + (size_t)b * BSTRIDE;
    const uint4* base4 = (const uint4*)base;
    int wv = threadIdx.x >> 6;
    int nq4 = sz >> 2;
    int half = nq4 >> 1;
    // ---- count pass (per-wave private histograms) ----
    for (int j = threadIdx.x; j < half; j += TPB) {
        uint4 p = base4[j];
        uint4 q = base4[j + half];
        atomicAdd(&cnt[wv][(p.x >> 17) & 127], 1);
        atomicAdd(&cnt[wv][(p.y >> 17) & 127], 1);
        atomicAdd(&cnt[wv][(p.z >> 17) & 127], 1);
        atomicAdd(&cnt[wv][(p.w >> 17) & 127], 1);
        atomicAdd(&cnt[wv][(q.x >> 17) & 127], 1);
        atomicAdd(&cnt[wv][(q.y >> 17) & 127], 1);
        atomicAdd(&cnt[wv][(q.z >> 17) & 127], 1);
        atomicAdd(&cnt[wv][(q.w >> 17) & 127], 1);
    }
    for (int j = half * 8 + threadIdx.x; j < sz; j += TPB) {
        unsigned p = base[j];
        atomicAdd(&cnt[wv][(p >> 17) & 127], 1);
    }
    __syncthreads();
    // ---- per-node totals + exclusive scan over 128 nodes ----
    int tot = 0;
    if (threadIdx.x < BNODES) {
        #pragma unroll
        for (int c = 0; c < 8; ++c) tot += cnt[c][threadIdx.x];
        eptr[threadIdx.x] = tot;              // will become inclusive scan
    }
    __syncthreads();
    for (int d = 1; d < BNODES; d <<= 1) {
        int add = 0;
        if (threadIdx.x < BNODES && threadIdx.x >= d) add = eptr[threadIdx.x - d];
        __syncthreads();
        if (threadIdx.x < BNODES) eptr[threadIdx.x] += add;
        __syncthreads();
    }
    if (threadIdx.x < BNODES) {
        int t = threadIdx.x;
        int ex = eptr[t] - tot;               // exclusive offset
        int run = ex;
        #pragma unroll
        for (int c = 0; c < 8; ++c) { int v = cnt[c][t]; cnt[c][t] = run; run += v; }
        rptr[b * BNODES + t] = ex;
        int node = (b << BSHIFT) + t;
        if (node < N) {
            float di = rsqrtf((float)(tot + 1));  // +1 self-loop
            dinv[node] = di;
            u[node] = di * x[node];
        }
    }
    __syncthreads();
    // ---- placement pass (same edge partition per wave -> private cursors) ----
    for (int j = threadIdx.x; j < half; j += TPB) {
        uint4 p = base4[j];
        uint4 q = base4[j + half];
        int pos;
        pos = atomicAdd(&cnt[wv][(p.x >> 17) & 127], 1); stage[pos] = p.x & 0x1FFFF;
        pos = atomicAdd(&cnt[wv][(p.y >> 17) & 127], 1); stage[pos] = p.y & 0x1FFFF;
        pos = atomicAdd(&cnt[wv][(p.z >> 17) & 127], 1); stage[pos] = p.z & 0x1FFFF;
        pos = atomicAdd(&cnt[wv][(p.w >> 17) & 127], 1); stage[pos] = p.w & 0x1FFFF;
        pos = atomicAdd(&cnt[wv][(q.x >> 17) & 127], 1); stage[pos] = q.x & 0x1FFFF;
        pos = atomicAdd(&cnt[wv][(q.y >> 17) & 127], 1); stage[pos] = q.y & 0x1FFFF;
        pos = atomicAdd(&cnt[wv][(q.z >> 17) & 127], 1); stage[pos] = q.z & 0x1FFFF;
        pos = atomicAdd(&cnt[wv][(q.w >> 17) & 127], 1); stage[pos] = q.w & 0x1FFFF;
    }
    for (int j = half * 8 + threadIdx.x; j < sz; j += TPB) {
        unsigned p = base[j];
        int pos = atomicAdd(&cnt[wv][(p >> 17) & 127], 1);
        stage[pos] = p & 0x1FFFF;
    }
    __syncthreads();
    // ---- coalesced in-place writeback (all reads of base done before here) ----
    for (int k = threadIdx.x; k < sz; k += TPB) base[k] = stage[k];
}

// ---------------- layer-1: atomic-free segmented sum + MLP ----------------

__global__ __launch_bounds__(TPB) void k_agg1(const unsigned* __restrict__ sorted,
                                              const int* __restrict__ gcur,
                                              const int* __restrict__ rptr,
                                              const float* __restrict__ dinv,
                                              const float* __restrict__ u,
                                              const float* __restrict__ W1,
                                              const float* __restrict__ b1,
                                              const float* __restrict__ W2,
                                              float2* __restrict__ w, int N) {
    __shared__ float sW1[64], sb1[64], sW2[128];
    __shared__ int sptr[BNODES + 1];
    int b = blockIdx.x;
    if (threadIdx.x < 64) { sW1[threadIdx.x] = W1[threadIdx.x]; sb1[threadIdx.x] = b1[threadIdx.x]; }
    else if (threadIdx.x < 192) sW2[threadIdx.x - 64] = W2[threadIdx.x - 64];
    if (threadIdx.x < BNODES) sptr[threadIdx.x] = rptr[b * BNODES + threadIdx.x];
    if (threadIdx.x == 0) sptr[BNODES] = gcur[b];
    __syncthreads();
    int t = threadIdx.x >> 2, k = threadIdx.x & 3;
    const unsigned* base = sorted + (size_t)b * BSTRIDE;
    int s0 = sptr[t], s1 = sptr[t + 1];
    float s = 0.f;
    for (int j = s0 + k; j < s1; j += 4) s += u[base[j] & 0x1FFFF];
    s += __shfl_xor(s, 1, 64);
    s += __shfl_xor(s, 2, 64);
    int node = (b << BSHIFT) + t;
    if (k == 0 && node < N) {
        float di = dinv[node];
        float sv = di * (s + u[node]);       // self-loop term dinv*u
        float z0 = 0.f, z1 = 0.f;
        #pragma unroll
        for (int j = 0; j < 64; ++j) {
            float h = fmaxf(fmaf(sv, sW1[j], sb1[j]), 0.f);
            z0 = fmaf(h, sW2[2 * j], z0);
            z1 = fmaf(h, sW2[2 * j + 1], z1);
        }
        w[node] = make_float2(di * z0, di * z1);  // pre-scaled by dinv[src]
    }
}

// ---- layer-2: atomic-free segmented float2 sum + log_softmax + partial ----

__global__ __launch_bounds__(TPB) void k_agg2(const unsigned* __restrict__ sorted,
                                              const int* __restrict__ gcur,
                                              const int* __restrict__ rptr,
                                              const float* __restrict__ dinv,
                                              const float2* __restrict__ w,
                                              const float* __restrict__ b2,
                                              float* __restrict__ accum, int N) {
    __shared__ int sptr[BNODES + 1];
    int b = blockIdx.x;
    if (threadIdx.x < BNODES) sptr[threadIdx.x] = rptr[b * BNODES + threadIdx.x];
    if (threadIdx.x == 0) sptr[BNODES] = gcur[b];
    __syncthreads();
    int t = threadIdx.x >> 2, k = threadIdx.x & 3;
    const unsigned* base = sorted + (size_t)b * BSTRIDE;
    int s0 = sptr[t], s1 = sptr[t + 1];
    float sx = 0.f, sy = 0.f;
    for (int j = s0 + k; j < s1; j += 4) {
        float2 v = w[base[j] & 0x1FFFF];
        sx += v.x;
        sy += v.y;
    }
    sx += __shfl_xor(sx, 1, 64); sx += __shfl_xor(sx, 2, 64);
    sy += __shfl_xor(sy, 1, 64); sy += __shfl_xor(sy, 2, 64);
    int node = (b << BSHIFT) + t;
    float l0 = 0.f, l1 = 0.f;
    if (k == 0 && node < N) {
        float di = dinv[node];
        float2 wi = w[node];
        float a0 = di * (sx + wi.x) + b2[0];
        float a1 = di * (sy + wi.y) + b2[1];
        float m = fmaxf(a0, a1);
        float lse = m + logf(expf(a0 - m) + expf(a1 - m));
        l0 = a0 - lse;
        l1 = a1 - lse;
    }
    #pragma unroll
    for (int off = 32; off > 0; off >>= 1) {
        l0 += __shfl_down(l0, off, 64);
        l1 += __shfl_down(l1, off, 64);
    }
    __shared__ float r0[TPB / 64], r1[TPB / 64];
    int wid = threadIdx.x >> 6, lane = threadIdx.x & 63;
    if (lane == 0) { r0[wid] = l0; r1[wid] = l1; }
    __syncthreads();
    if (threadIdx.x == 0) {
        float t0 = 0.f, t1 = 0.f;
        #pragma unroll
        for (int kk = 0; kk < TPB / 64; ++kk) { t0 += r0[kk]; t1 += r1[kk]; }
        accum[2 * b]     = t0;   // private slot, plain store
        accum[2 * b + 1] = t1;
    }
}

// ---------------- final reduction over per-block partials ----------------

#define RTPB 1024
__global__ __launch_bounds__(RTPB) void k_reduce_final(const float* __restrict__ accum,
                                                       int nb, float* __restrict__ out,
                                                       float invN) {
    float t0 = 0.f, t1 = 0.f;
    for (int i = threadIdx.x; i < nb; i += RTPB) {
        t0 += accum[2 * i];
        t1 += accum[2 * i + 1];
    }
    #pragma unroll
    for (int off = 32; off > 0; off >>= 1) {
        t0 += __shfl_down(t0, off, 64);
        t1 += __shfl_down(t1, off, 64);
    }
    __shared__ float s0[RTPB / 64], s1[RTPB / 64];
    int wid = threadIdx.x >> 6, lane = threadIdx.x & 63;
    if (lane == 0) { s0[wid] = t0; s1[wid] = t1; }
    __syncthreads();
    if (threadIdx.x == 0) {
        float a = 0.f, b = 0.f;
        #pragma unroll
        for (int k = 0; k < RTPB / 64; ++k) { a += s0[k]; b += s1[k]; }
        out[0] = a * invN;
        out[1] = b * invN;
    }
}

__global__ void k_finalize(const float* __restrict__ accum, float* __restrict__ out, float invN) {
    out[0] = accum[0] * invN;
    out[1] = accum[1] * invN;
}

// ---------------- fallback (global-atomic path) ----------------

#define FTPB 256
__global__ void k_hist(const int* __restrict__ dst, int E, int* __restrict__ deg) {
    int e = blockIdx.x * FTPB + threadIdx.x;
    if (e < E) atomicAdd(&deg[dst[e]], 1);
}
__global__ void k_dinv_u(const int* __restrict__ deg, const float* __restrict__ x,
                         float* __restrict__ dinv, float* __restrict__ u, int N) {
    int i = blockIdx.x * FTPB + threadIdx.x;
    if (i < N) {
        float di = rsqrtf((float)(deg[i] + 1));
        dinv[i] = di;
        u[i] = di * x[i];
    }
}
__global__ void k_scatter1(const int* __restrict__ ei, int E,
                           const float* __restrict__ u, float* __restrict__ t) {
    int e = blockIdx.x * FTPB + threadIdx.x;
    if (e < E) atomicAdd(&t[ei[E + e]], u[ei[e]]);
}
__global__ void k_node_mid_fb(const float* __restrict__ dinv, const float* __restrict__ u,
                              const float* __restrict__ t,
                              const float* __restrict__ W1, const float* __restrict__ b1,
                              const float* __restrict__ W2, float2* __restrict__ w, int N) {
    __shared__ float sW1[64], sb1[64], sW2[128];
    if (threadIdx.x < 64) { sW1[threadIdx.x] = W1[threadIdx.x]; sb1[threadIdx.x] = b1[threadIdx.x]; }
    if (threadIdx.x < 128) sW2[threadIdx.x] = W2[threadIdx.x];
    __syncthreads();
    int i = blockIdx.x * FTPB + threadIdx.x;
    if (i < N) {
        float di = dinv[i];
        float s = di * (t[i] + u[i]);
        float z0 = 0.f, z1 = 0.f;
        #pragma unroll
        for (int j = 0; j < 64; ++j) {
            float h = fmaxf(fmaf(s, sW1[j], sb1[j]), 0.f);
            z0 = fmaf(h, sW2[2 * j], z0);
            z1 = fmaf(h, sW2[2 * j + 1], z1);
        }
        w[i] = make_float2(di * z0, di * z1);
    }
}
__global__ void k_scatter2(const int* __restrict__ ei, int E,
                           const float2* __restrict__ w, float* __restrict__ acc) {
    int e = blockIdx.x * FTPB + threadIdx.x;
    if (e < E) {
        float2 ws = w[ei[e]];
        int d = ei[E + e];
        atomicAdd(&acc[2 * d], ws.x);
        atomicAdd(&acc[2 * d + 1], ws.y);
    }
}
__global__ void k_node_out_fb(const float* __restrict__ dinv, const float2* __restrict__ w,
                              const float2* __restrict__ acc, const float* __restrict__ b2,
                              float* __restrict__ accum, int N) {
    int i = blockIdx.x * FTPB + threadIdx.x;
    float l0 = 0.f, l1 = 0.f;
    if (i < N) {
        float di = dinv[i];
        float2 a = acc[i];
        float2 ww = w[i];
        float a0 = di * (a.x + ww.x) + b2[0];
        float a1 = di * (a.y + ww.y) + b2[1];
        float m = fmaxf(a0, a1);
        float lse = m + logf(expf(a0 - m) + expf(a1 - m));
        l0 = a0 - lse;
        l1 = a1 - lse;
    }
    #pragma unroll
    for (int off = 32; off > 0; off >>= 1) {
        l0 += __shfl_down(l0, off, 64);
        l1 += __shfl_down(l1, off, 64);
    }
    __shared__ float s0[FTPB / 64], s1[FTPB / 64];
    int wid = threadIdx.x >> 6, lane = threadIdx.x & 63;
    if (lane == 0) { s0[wid] = l0; s1[wid] = l1; }
    __syncthreads();
    if (threadIdx.x == 0) {
        float t0 = 0.f, t1 = 0.f;
        #pragma unroll
        for (int k = 0; k < FTPB / 64; ++k) { t0 += s0[k]; t1 += s1[k]; }
        atomicAdd(&accum[0], t0);
        atomicAdd(&accum[1], t1);
    }
}

extern "C" void kernel_launch(void* const* d_in, const int* in_sizes, int n_in,
                              void* d_out, int out_size, void* d_ws, size_t ws_size,
                              hipStream_t stream) {
    const float* x  = (const float*)d_in[0];
    const int*   ei = (const int*)d_in[1];
    const float* W1 = (const float*)d_in[2];
    const float* b1 = (const float*)d_in[3];
    const float* W2 = (const float*)d_in[4];
    const float* b2 = (const float*)d_in[5];
    float* out = (float*)d_out;

    const int N = in_sizes[0];
    const int E = in_sizes[1] / 2;
    const int nbuck = (N + BNODES - 1) >> BSHIFT;
    const int gridN = (N + FTPB - 1) / FTPB;
    const int gridE = (E + FTPB - 1) / FTPB;

    size_t offPacked = 0;
    size_t offW      = offPacked + (size_t)nbuck * BSTRIDE * 4;
    size_t offDinv   = offW + (size_t)N * 8;
    size_t offU      = offDinv + (size_t)N * 4;
    size_t offGcur   = offU + (size_t)N * 4;
    size_t offAccum  = offGcur + (size_t)nbuck * 4;
    size_t offRptr   = offAccum + (size_t)2 * nbuck * 4;
    size_t need      = offRptr + (size_t)nbuck * BNODES * 4;

    if (ws_size >= need && nbuck <= MAXBUCK && N <= (1 << 17)) {
        unsigned* packed = (unsigned*)((char*)d_ws + offPacked);
        float2*   w      = (float2*)((char*)d_ws + offW);
        float*    dinv   = (float*)((char*)d_ws + offDinv);
        float*    u      = (float*)((char*)d_ws + offU);
        int*      gcur   = (int*)((char*)d_ws + offGcur);
        float*    accum  = (float*)((char*)d_ws + offAccum);
        int*      rptr   = (int*)((char*)d_ws + offRptr);

        hipMemsetAsync(gcur, 0, (size_t)nbuck * 4, stream);

        int epb = (((E + SORT_BLK - 1) / SORT_BLK) + 3) & ~3;

        k_sort<<<SORT_BLK, TPB, 0, stream>>>(ei, E, epb, nbuck, gcur, packed);
        k_csr<<<nbuck, TPB, 0, stream>>>(packed, gcur, x, dinv, u, rptr, N);
        k_agg1<<<nbuck, TPB, 0, stream>>>(packed, gcur, rptr, dinv, u, W1, b1, W2, w, N);
        k_agg2<<<nbuck, TPB, 0, stream>>>(packed, gcur, rptr, dinv, (const float2*)w, b2, accum, N);
        k_reduce_final<<<1, RTPB, 0, stream>>>(accum, nbuck, out, 1.0f / (float)N);
    } else {
        int*   deg   = (int*)d_ws;
        float* t     = (float*)(deg + N);
        float* acc   = t + N;
        float* accum = acc + 2 * N;
        float* dinv  = accum + 2;
        float* u     = dinv + N;
        float2* w    = (float2*)(u + N);
        hipMemsetAsync(d_ws, 0, (size_t)(4 * N + 2) * sizeof(float), stream);
        k_hist<<<gridE, FTPB, 0, stream>>>(ei + E, E, deg);
        k_dinv_u<<<gridN, FTPB, 0, stream>>>(deg, x, dinv, u, N);
        k_scatter1<<<gridE, FTPB, 0, stream>>>(ei, E, u, t);
        k_node_mid_fb<<<gridN, FTPB, 0, stream>>>(dinv, u, t, W1, b1, W2, w, N);
        k_scatter2<<<gridE, FTPB, 0, stream>>>(ei, E, w, acc);
        k_node_out_fb<<<gridN, FTPB, 0, stream>>>(dinv, w, (const float2*)acc, b2, accum, N);
        k_finalize<<<1, 64, 0, stream>>>(accum, out, 1.0f / (float)N);
    }
}